// Round 3
// baseline (15242.426 us; speedup 1.0000x reference)
//
#include <hip/hip_runtime.h>
#include <cstdint>
#include <cstddef>

typedef _Float16 f16;
typedef _Float16 f16x2 __attribute__((ext_vector_type(2)));

constexpr int Bn = 64, In = 128, Tn = 1024, Hn = 256, Gn = 1024; // Gn = 4H
constexpr int WREG = 192;   // f16x2 weights per thread in VGPRs (384KB/CU)
constexpr int NCH  = 16;    // float4 weight chunks per thread in LDS (128KB/CU)

// ---------------- helpers ----------------

__device__ __forceinline__ float fdot2(f16x2 a, f16x2 b, float c) {
#if defined(__has_builtin)
#if __has_builtin(__builtin_amdgcn_fdot2)
  return __builtin_amdgcn_fdot2(a, b, c, false);
#else
  return c + (float)a.x * (float)b.x + (float)a.y * (float)b.y;
#endif
#else
  return c + (float)a.x * (float)b.x + (float)a.y * (float)b.y;
#endif
}

__device__ __forceinline__ float rcp_(float x) {
#if defined(__has_builtin)
#if __has_builtin(__builtin_amdgcn_rcpf)
  return __builtin_amdgcn_rcpf(x);
#else
  return 1.f / x;
#endif
#else
  return 1.f / x;
#endif
}

__device__ __forceinline__ float sigm(float x) {
  return rcp_(1.f + __expf(-x));
}

__device__ __forceinline__ float tanh_(float x) {
  float xc = fminf(fmaxf(x, -15.f), 15.f);
  float e = __expf(-2.f * xc);
  return (1.f - e) * rcp_(1.f + e);
}

union F4H { float4 f4; f16x2 h2[4]; };

// ---------------- pack W_hh (f32 [1024][256]) into rec-kernel layout ----------------
// rec thread j owns rows r0=j (i|f gate) and r1=j+512 (g|o gate).
// wreg[k*512+j]: k<128      -> row j,     col2 k       (cols 2k,2k+1)
//                128<=k<192 -> row j+512, col2 k-128   (cols 0..127)
// wlds[(q*512+j)*4+m], q<16 -> row j+512, col2 64+4q+m (cols 128..255)
__global__ void pack_whh(const float* __restrict__ Whh,
                         f16x2* __restrict__ wreg, f16x2* __restrict__ wlds) {
  const int j = blockIdx.x;   // 0..511
  const int k = threadIdx.x;  // 0..255
  int row, col2;
  if (k < 128)       { row = j;       col2 = k; }
  else if (k < WREG) { row = j + 512; col2 = k - 128; }
  else               { row = j + 512; col2 = 64 + (k - WREG); }
  const float2* w2 = (const float2*)Whh;
  float2 v = w2[(size_t)row * (Hn / 2) + col2];
  f16x2 h; h.x = (f16)v.x; h.y = (f16)v.y;
  if (k < WREG) {
    wreg[(size_t)k * 512 + j] = h;
  } else {
    int idx = k - WREG;               // 0..63
    int q = idx >> 2, m = idx & 3;
    wlds[((size_t)q * 512 + j) * 4 + m] = h;
  }
}

// ---------------- input GEMM (segment): pre[b,tl,g] = sum_i x[b,i,tbase+tl]*W_ih[g,i] + b_ih[g]+b_hh[g]
__global__ __launch_bounds__(256, 4) void gemm_pre(
    const float* __restrict__ x, const float* __restrict__ Wih,
    const float* __restrict__ bih, const float* __restrict__ bhh,
    float* __restrict__ pre, int Ts, int tbase) {
  __shared__ float xs[64][64];   // [i][tt]
  __shared__ float wsh[64][65];  // [gg][i], padded
  const int bb = blockIdx.z, t0 = blockIdx.y * 64, g0 = blockIdx.x * 64;
  const int tid = threadIdx.x;
  const int tx = tid & 15, ty = tid >> 4;
  const int l64 = tid & 63, h2b = tid >> 6;
  float acc[4][4] = {};

  for (int ih = 0; ih < 2; ++ih) {
#pragma unroll 4
    for (int s = 0; s < 16; ++s) {
      int i = h2b + s * 4;
      xs[i][l64] = x[(size_t)bb * In * Tn + (size_t)(ih * 64 + i) * Tn + tbase + t0 + l64];
      wsh[i][l64] = Wih[(size_t)(g0 + i) * In + ih * 64 + l64];
    }
    __syncthreads();
#pragma unroll 8
    for (int i = 0; i < 64; ++i) {
      float4 xv = *(const float4*)&xs[i][ty * 4];
      float w0 = wsh[tx * 4 + 0][i];
      float w1 = wsh[tx * 4 + 1][i];
      float w2 = wsh[tx * 4 + 2][i];
      float w3 = wsh[tx * 4 + 3][i];
      acc[0][0] += xv.x * w0; acc[0][1] += xv.x * w1; acc[0][2] += xv.x * w2; acc[0][3] += xv.x * w3;
      acc[1][0] += xv.y * w0; acc[1][1] += xv.y * w1; acc[1][2] += xv.y * w2; acc[1][3] += xv.y * w3;
      acc[2][0] += xv.z * w0; acc[2][1] += xv.z * w1; acc[2][2] += xv.z * w2; acc[2][3] += xv.z * w3;
      acc[3][0] += xv.w * w0; acc[3][1] += xv.w * w1; acc[3][2] += xv.w * w2; acc[3][3] += xv.w * w3;
    }
    __syncthreads();
  }

  float bs[4];
#pragma unroll
  for (int q = 0; q < 4; ++q) {
    int g = g0 + tx * 4 + q;
    bs[q] = bih[g] + bhh[g];
  }
#pragma unroll
  for (int ti = 0; ti < 4; ++ti) {
    int tl = t0 + ty * 4 + ti;
    size_t idx = ((size_t)bb * Ts + tl) * Gn + g0 + tx * 4;
    float4 fv;
    fv.x = acc[ti][0] + bs[0]; fv.y = acc[ti][1] + bs[1];
    fv.z = acc[ti][2] + bs[2]; fv.w = acc[ti][3] + bs[3];
    *(float4*)&pre[idx] = fv;
  }
}

// ---------------- recurrent kernel (one segment): one block = one batch element ----------------
__global__ __launch_bounds__(512, 2) void lstm_rec(
    const f16x2* __restrict__ wreg, const float4* __restrict__ wldsg,
    const float* __restrict__ pre, float* __restrict__ out,
    float* __restrict__ cws, f16x2* __restrict__ hws,
    int seg0, int Ts, int tbase) {
  __shared__ float4 wlds4[NCH * 512];  // 128KB
  __shared__ f16x2  hbuf[128];         // 512B  (256 f16 h-state)
  __shared__ float  ig[256];           // 1KB   (i*g products)
  __shared__ f16    hist[256 * 33];    // 16.9KB (output staging, +1 pad col)

  const int j  = threadIdx.x;  // 0..511
  const int bb = blockIdx.x;   // batch element

  // persistent weights
  f16x2 w[WREG];
#pragma unroll
  for (int k = 0; k < WREG; ++k) w[k] = wreg[(size_t)k * 512 + j];
#pragma unroll
  for (int q = 0; q < NCH; ++q) wlds4[q * 512 + j] = wldsg[(size_t)q * 512 + j];
  if (j < 128) {
    f16x2 z = {};
    hbuf[j] = seg0 ? z : hws[bb * 128 + j];
  }
  __syncthreads();

  const size_t pbase = (size_t)bb * Ts * Gn;
  float* outb = out + (size_t)bb * Hn * Tn + tbase;

  float c = 0.f;
  if (j >= 256 && !seg0) c = cws[bb * 256 + (j - 256)];
  float p0 = pre[pbase + j];
  float p1 = pre[pbase + 512 + j];

  const float4* hv4 = (const float4*)hbuf;

  for (int t = 0; t < Ts; ++t) {
    float a0 = 0.f, a1 = 0.f, b0 = 0.f, b1 = 0.f;
    // cols 0..127 of both rows: all from registers
#pragma unroll
    for (int k0 = 0; k0 < 16; ++k0) {
      F4H hu; hu.f4 = hv4[k0];
      a0 = fdot2(w[4 * k0 + 0], hu.h2[0], a0);
      a1 = fdot2(w[4 * k0 + 1], hu.h2[1], a1);
      a0 = fdot2(w[4 * k0 + 2], hu.h2[2], a0);
      a1 = fdot2(w[4 * k0 + 3], hu.h2[3], a1);
      b0 = fdot2(w[128 + 4 * k0 + 0], hu.h2[0], b0);
      b1 = fdot2(w[128 + 4 * k0 + 1], hu.h2[1], b1);
      b0 = fdot2(w[128 + 4 * k0 + 2], hu.h2[2], b0);
      b1 = fdot2(w[128 + 4 * k0 + 3], hu.h2[3], b1);
    }
    // cols 128..255: row r0 from registers, row r1 from LDS
#pragma unroll
    for (int k0 = 16; k0 < 32; ++k0) {
      F4H hu; hu.f4 = hv4[k0];
      F4H wu; wu.f4 = wlds4[(k0 - 16) * 512 + j];
      a0 = fdot2(w[4 * k0 + 0], hu.h2[0], a0);
      a1 = fdot2(w[4 * k0 + 1], hu.h2[1], a1);
      a0 = fdot2(w[4 * k0 + 2], hu.h2[2], a0);
      a1 = fdot2(w[4 * k0 + 3], hu.h2[3], a1);
      b0 = fdot2(wu.h2[0], hu.h2[0], b0);
      b1 = fdot2(wu.h2[1], hu.h2[1], b1);
      b0 = fdot2(wu.h2[2], hu.h2[2], b0);
      b1 = fdot2(wu.h2[3], hu.h2[3], b1);
    }
    float g0raw = a0 + a1 + p0;  // row j:     i (j<256) or f (j>=256)
    float g1raw = b0 + b1 + p1;  // row j+512: g (j<256) or o (j>=256)

    // prefetch next step's pre
    if (t + 1 < Ts) {
      size_t o = pbase + (size_t)(t + 1) * Gn + j;
      p0 = pre[o];
      p1 = pre[o + 512];
    }

    float act0, act1;
    if (j < 256) {
      act0 = sigm(g0raw);    // i
      act1 = tanh_(g1raw);   // g
      ig[j] = act0 * act1;
    } else {
      act0 = sigm(g0raw);    // f
      act1 = sigm(g1raw);    // o
    }
    __syncthreads();
    if (j >= 256) {
      int n = j - 256;
      c = act0 * c + ig[n];
      float th = tanh_(c);
      float h = act1 * th;
      hist[n * 33 + (t & 31)] = (f16)fmaxf(h, 0.f);
      ((f16*)hbuf)[n] = (f16)h;
    }
    __syncthreads();

    if ((t & 31) == 31) {
      int t0 = t - 31;
#pragma unroll
      for (int v = 0; v < 16; ++v) {
        int flat = v * 512 + j;
        int n = flat >> 5, tt = flat & 31;
        outb[(size_t)n * Tn + t0 + tt] = (float)hist[n * 33 + tt];
      }
      // no extra barrier needed: next hist write is after next step's first barrier
    }
  }

  // persist state for next segment
  if (j >= 256) cws[bb * 256 + (j - 256)] = c;
  if (j < 128) hws[bb * 128 + j] = hbuf[j];
}

// ---------------- launch ----------------
extern "C" void kernel_launch(void* const* d_in, const int* in_sizes, int n_in,
                              void* d_out, int out_size, void* d_ws, size_t ws_size,
                              hipStream_t stream) {
  const float* x   = (const float*)d_in[0];
  const float* Wih = (const float*)d_in[1];
  const float* Whh = (const float*)d_in[2];
  const float* bih = (const float*)d_in[3];
  const float* bhh = (const float*)d_in[4];
  float* out = (float*)d_out;
  char* ws = (char*)d_ws;

  f16x2* wreg  = (f16x2*)ws;                   // 384KB
  f16x2* wldsg = (f16x2*)(ws + 384 * 1024);    // 128KB -> 512KB
  float* cws   = (float*)(ws + 512 * 1024);    // 64KB  -> 576KB
  f16x2* hws   = (f16x2*)(ws + 576 * 1024);    // 32KB  -> 608KB
  float* pre   = (float*)(ws + (1 << 20));     // segment pre buffer

  // choose largest segment length whose fp32 pre fits in ws
  int Ts = 64;
  for (int cand = 1024; cand >= 64; cand >>= 1) {
    size_t need = (size_t)(1 << 20) + (size_t)Bn * cand * Gn * 4;
    if (need <= ws_size) { Ts = cand; break; }
  }
  int nseg = Tn / Ts;

  pack_whh<<<dim3(512), dim3(256), 0, stream>>>(Whh, wreg, wldsg);

  for (int s = 0; s < nseg; ++s) {
    dim3 gg(16, Ts / 64, 64);
    gemm_pre<<<gg, dim3(256), 0, stream>>>(x, Wih, bih, bhh, pre, Ts, s * Ts);
    lstm_rec<<<dim3(64), dim3(512), 0, stream>>>(
        wreg, (const float4*)wldsg, pre, out, cws, hws, (s == 0) ? 1 : 0, Ts, s * Ts);
  }
}